// Round 6
// baseline (155.019 us; speedup 1.0000x reference)
//
#include <hip/hip_runtime.h>

// Problem constants (from reference): B=32, M=32, C=1024, R=28
#define Rr 28
#define Bb 32
#define Mm 32
#define Cc 1024
#define CT 64   // channels per block (4 waves x 16 channels)

// ---------------------------------------------------------------------------
// Single fused kernel, BARRIER-FREE streaming phase.
// Grid = 512 blocks = (32 batches x 16 channel-tiles), 2 blocks/CU.
//
// XCD-aware mapping: all 16 blocks of a batch share bid%8 (= XCD under the
// round-robin heuristic) -> each batch's 98 KB mask region is fetched once
// and L2/L3-served to the other 15 blocks.  Perf heuristic only.
//
// Phase 0: col_s[m][r] = sum_i Mk[b,m,i,r] (224 threads, float4 segments),
//          overlapped with the first F prefetch's HBM latency.
// Phase 1: row sums.  Each WAVE owns a private contiguous 16-channel slice
//          (3136 float4) and a private part_s region -> the float4->row
//          transpose is wave-internal (ds_write then ds_read, ordered by
//          lgkmcnt; wave-synchronous, NO __syncthreads).  part_s is
//          parity-double-buffered (k&1) so iteration k+1's writes can't
//          clobber iteration k's reads.  7 iterations, 2-deep prefetch.
//          ZERO barriers -> all 8 waves/CU stream independently; the HBM
//          request stream never drains on block-wide convoys.
// Phase 2: S[b,m,c0+cl] = (1/784) * sum_r col_s[m][r] * row_s[cl][r],
//          after the kernel's single __syncthreads().
//
// LDS: part 8*448*4 = 14.3 KB + row 7.4 KB + col 3.7 KB = 25.4 KB.
// Bank checks: part writes q*64+l -> bank l%32, 2 lanes/bank (free);
// part reads 7l+j -> lanes l,l+32 alias one bank, 2-way (free);
// stride-29 padding on row_s/col_s keeps phase 2 conflict-free.
// ---------------------------------------------------------------------------
__global__ __launch_bounds__(256) void fused_all(
    const float* __restrict__ F, const float* __restrict__ Mk,
    float* __restrict__ S) {
    __shared__ float part_s[8 * 448];     // 4 waves x 2 parity buffers x 448
    __shared__ float row_s[CT * 29];      // 64 ch x 28 row-sums, padded
    __shared__ float col_s[Mm * 29];      // 32 masks x 28 col-sums, padded

    const int bid = blockIdx.x;
    const int xcd = bid & 7;
    const int kk  = bid >> 3;             // 0..63
    const int b   = xcd * 4 + (kk >> 4);  // batch: all 16 tiles share bid%8
    const int c0  = (kk & 15) * CT;       // channel-tile base
    const int t   = threadIdx.x;
    const int wv  = t >> 6;               // wave id 0..3
    const int l   = t & 63;               // lane

    // wave-private F slice: 16 channels = 3136 float4, contiguous
    const float4* Fw4 =
        (const float4*)(F + ((size_t)b * Cc + c0 + wv * 16) * (Rr * Rr));

    // prefetch wave-subtile 0; HBM latency hides under phase 0
    float4 va[7], vb[7];
#pragma unroll
    for (int q = 0; q < 7; ++q) va[q] = Fw4[q * 64 + l];

    // Phase 0: col sums.  thread -> (mask m, 4-column segment seg).
    if (t < Mm * 7) {
        const int m = t / 7, seg = t - m * 7;
        const float4* Mp = (const float4*)(Mk + ((size_t)b * Mm + m) * (Rr * Rr)) + seg;
        float4 a = {0.f, 0.f, 0.f, 0.f};
#pragma unroll
        for (int i = 0; i < Rr; ++i) {
            float4 w = Mp[i * 7];         // row i, cols seg*4..seg*4+3
            a.x += w.x; a.y += w.y; a.z += w.z; a.w += w.w;
        }
        const int r0 = seg * 4;
        col_s[m * 29 + r0 + 0] = a.x;
        col_s[m * 29 + r0 + 1] = a.y;
        col_s[m * 29 + r0 + 2] = a.z;
        col_s[m * 29 + r0 + 3] = a.w;
    }

    // Phase 1 body: issue subtile k+1 into NXT, transpose+reduce subtile k.
    // All LDS traffic is wave-private: no barriers anywhere in this loop.
#define BODY(k, CUR, NXT)                                                  \
    {                                                                      \
        if ((k) < 6) {                                                     \
            const float4* p = Fw4 + ((k) + 1) * 448;                       \
            _Pragma("unroll")                                              \
            for (int q = 0; q < 7; ++q) NXT[q] = p[q * 64 + l];            \
        }                                                                  \
        float* pw = part_s + (wv * 2 + ((k) & 1)) * 448;                   \
        _Pragma("unroll")                                                  \
        for (int q = 0; q < 7; ++q)                                        \
            pw[q * 64 + l] = (CUR[q].x + CUR[q].y) + (CUR[q].z + CUR[q].w);\
        float rs = 0.f;                                                    \
        _Pragma("unroll")                                                  \
        for (int j = 0; j < 7; ++j) rs += pw[l * 7 + j];                   \
        int rowI = (k) * 64 + l;      /* row within wave slice, 0..447 */  \
        int ch = rowI / Rr, r = rowI - ch * Rr;                            \
        row_s[(wv * 16 + ch) * 29 + r] = rs;                               \
    }

    BODY(0, va, vb)
    BODY(1, vb, va)
    BODY(2, va, vb)
    BODY(3, vb, va)
    BODY(4, va, vb)
    BODY(5, vb, va)
    BODY(6, va, vb)
#undef BODY

    __syncthreads();   // the kernel's ONLY barrier: row_s/col_s -> phase 2

    // Phase 2: tiny GEMM from LDS.
    const int cl = t & (CT - 1);          // lane-consecutive channel -> coalesced stores
    const int mq = t >> 6;                // 0..3, wave-uniform
    float rreg[Rr];
#pragma unroll
    for (int r = 0; r < Rr; ++r) rreg[r] = row_s[cl * 29 + r];

    const float inv = 1.0f / (Rr * Rr);
    for (int m = mq; m < Mm; m += 4) {
        float acc = 0.f;
#pragma unroll
        for (int r = 0; r < Rr; ++r)
            acc += col_s[m * 29 + r] * rreg[r];   // wave-uniform broadcast read
        S[((size_t)b * Mm + m) * Cc + c0 + cl] = acc * inv;
    }
}

extern "C" void kernel_launch(void* const* d_in, const int* in_sizes, int n_in,
                              void* d_out, int out_size, void* d_ws, size_t ws_size,
                              hipStream_t stream) {
    const float* F  = (const float*)d_in[0];   // (B, C, R, R) fp32
    const float* Mk = (const float*)d_in[1];   // (B, M, R, R) fp32
    float* S = (float*)d_out;                  // (B, M, C) fp32

    fused_all<<<Bb * 16, 256, 0, stream>>>(F, Mk, S);
}

// Round 8
// 146.748 us; speedup vs baseline: 1.0564x; 1.0564x over previous
//
#include <hip/hip_runtime.h>

// Problem constants (from reference): B=32, M=32, C=1024, R=28
#define Rr 28
#define Bb 32
#define Mm 32
#define Cc 1024
#define CT 64   // channels per block

// ---------------------------------------------------------------------------
// Single fused kernel (R5 structure) + NON-TEMPORAL F reads.
//
// Why nt: the harness poisons the 392 MiB workspace with fillBuffer right
// before each run, leaving L2/L3 full of DIRTY lines.  Ordinary F loads
// allocate in L2/L3 and evict those dirty lines -> ~100 MB of forced
// writebacks compete with our reads (~2x effective kernel traffic; explains
// why coalescing/pipelining/barrier levers were all null).  F lines are
// read exactly once by exactly one lane -> nt (no-allocate) is free, and
// the dirty fill lines die in-cache when the next fill overwrites them.
// Masks stay cached (16 blocks/batch share them via L2).
//
// NOTE: __builtin_nontemporal_load requires a native clang vector type,
// not HIP_vector_type<float,4> -> use ext_vector_type(4) for the nt path.
//
// Grid = 512 blocks = (32 batches x 16 channel-tiles), 2 blocks/CU.
// XCD-aware mapping: all 16 blocks of a batch share bid%8.
// Phase 0: col_s[m][r] = sum_i Mk[b,m,i,r] (224 threads, float4 segments).
// Phase 1: row sums, 7 subtiles, 2-deep double-buffered nt prefetch,
//          LDS transpose (part_s) -> 7:1 reduce -> row_s.
// Phase 2: S[b,m,c0+cl] = (1/784) * sum_r col_s[m][r] * row_s[cl][r].
// LDS 18.3 KB; stride-29 padding keeps every LDS access <=2 lanes/bank.
// ---------------------------------------------------------------------------

typedef float f32x4 __attribute__((ext_vector_type(4)));

__device__ __forceinline__ f32x4 ntload(const float* p) {
    return __builtin_nontemporal_load((const f32x4*)p);
}

__global__ __launch_bounds__(256) void fused_all(
    const float* __restrict__ F, const float* __restrict__ Mk,
    float* __restrict__ S) {
    __shared__ float part_s[7 * 256];     // per-float4 partials for one subtile
    __shared__ float row_s[CT * 29];      // 64 ch x 28 row-sums, padded
    __shared__ float col_s[Mm * 29];      // 32 masks x 28 col-sums, padded

    const int bid = blockIdx.x;
    const int xcd = bid & 7;
    const int kk  = bid >> 3;             // 0..63
    const int b   = xcd * 4 + (kk >> 4);  // batch: all 16 tiles share bid%8
    const int c0  = (kk & 15) * CT;       // channel-tile base
    const int t   = threadIdx.x;

    const float* Fb = F + ((size_t)b * Cc + c0) * (Rr * Rr);

    // prefetch F subtile 0 (nt); its HBM latency hides under phase 0
    f32x4 va[7], vb[7];
#pragma unroll
    for (int q = 0; q < 7; ++q) va[q] = ntload(Fb + 4 * (q * 256 + t));

    // Phase 0: col sums.  thread -> (mask m, 4-column segment seg).  Cached.
    if (t < Mm * 7) {
        const int m = t / 7, seg = t - m * 7;
        const float4* Mp = (const float4*)(Mk + ((size_t)b * Mm + m) * (Rr * Rr)) + seg;
        float4 a = {0.f, 0.f, 0.f, 0.f};
#pragma unroll
        for (int i = 0; i < Rr; ++i) {
            float4 w = Mp[i * 7];         // row i, cols seg*4..seg*4+3
            a.x += w.x; a.y += w.y; a.z += w.z; a.w += w.w;
        }
        const int r0 = seg * 4;
        col_s[m * 29 + r0 + 0] = a.x;
        col_s[m * 29 + r0 + 1] = a.y;
        col_s[m * 29 + r0 + 2] = a.z;
        col_s[m * 29 + r0 + 3] = a.w;
    }

    // Phase 1 body: issue tile k+1 into NXT (nt), then consume CUR (tile k).
#define BODY(k, CUR, NXT)                                                  \
    {                                                                      \
        if ((k) < 6) {                                                     \
            const float* p = Fb + ((k) + 1) * 7168;                        \
            _Pragma("unroll")                                              \
            for (int q = 0; q < 7; ++q)                                    \
                NXT[q] = ntload(p + 4 * (q * 256 + t));                    \
        }                                                                  \
        float s[7];                                                        \
        _Pragma("unroll")                                                  \
        for (int q = 0; q < 7; ++q)                                        \
            s[q] = (CUR[q].x + CUR[q].y) + (CUR[q].z + CUR[q].w);          \
        _Pragma("unroll")                                                  \
        for (int q = 0; q < 7; ++q) part_s[q * 256 + t] = s[q];            \
        __syncthreads();                                                   \
        int rg = (k) * 256 + t;                                            \
        int ch = rg / Rr, r = rg - ch * Rr;                                \
        float rs = 0.f;                                                    \
        _Pragma("unroll")                                                  \
        for (int j = 0; j < 7; ++j) rs += part_s[t * 7 + j];               \
        row_s[ch * 29 + r] = rs;                                           \
        __syncthreads(); /* WAR: part_s reused next subtile */             \
    }

    BODY(0, va, vb)
    BODY(1, vb, va)
    BODY(2, va, vb)
    BODY(3, vb, va)
    BODY(4, va, vb)
    BODY(5, vb, va)
    BODY(6, va, vb)
#undef BODY

    // Phase 2: tiny GEMM from LDS.
    const int cl = t & (CT - 1);          // lane-consecutive channel -> coalesced stores
    const int mq = t >> 6;                // 0..3, wave-uniform
    float rreg[Rr];
#pragma unroll
    for (int r = 0; r < Rr; ++r) rreg[r] = row_s[cl * 29 + r];

    const float inv = 1.0f / (Rr * Rr);
    for (int m = mq; m < Mm; m += 4) {
        float acc = 0.f;
#pragma unroll
        for (int r = 0; r < Rr; ++r)
            acc += col_s[m * 29 + r] * rreg[r];   // wave-uniform broadcast read
        S[((size_t)b * Mm + m) * Cc + c0 + cl] = acc * inv;
    }
}

extern "C" void kernel_launch(void* const* d_in, const int* in_sizes, int n_in,
                              void* d_out, int out_size, void* d_ws, size_t ws_size,
                              hipStream_t stream) {
    const float* F  = (const float*)d_in[0];   // (B, C, R, R) fp32
    const float* Mk = (const float*)d_in[1];   // (B, M, R, R) fp32
    float* S = (float*)d_out;                  // (B, M, C) fp32

    fused_all<<<Bb * 16, 256, 0, stream>>>(F, Mk, S);
}